// Round 2
// baseline (534.908 us; speedup 1.0000x reference)
//
#include <hip/hip_runtime.h>

// Round 1: resubmission of Round-0 baseline (previous bench was an infra
// failure — "MI355X container failed twice" — no kernel signal received).

// Problem constants
#define T_SEQ 1024
#define B_SZ  2
#define E_DIM 1024
#define H_N   16
#define D_HD  64
#define NROWS (T_SEQ * B_SZ)          // 2048
#define CHUNK 64
#define NCHUNK (T_SEQ / CHUNK)        // 16
#define BH (B_SZ * H_N)               // 32
#define NBHTD (B_SZ * H_N * T_SEQ * D_HD)  // 2,097,152 per matrix

// ---------------------------------------------------------------------------
// Kernel 1: in-projection. out = X @ W_m^T + b_m for m in {q,k,v}.
// X is (T,B,E) flattened as rows r = t*B+b. Output written directly into
// (B,H,T,D) layout: qkv[m][((b*H+h)*T+t)*D + d].
// 128x128 tile, BK=32, 256 threads, 8x8 micro-tile per thread, fp32.
// ---------------------------------------------------------------------------
__global__ __launch_bounds__(256) void k_inproj(
    const float* __restrict__ q_in, const float* __restrict__ k_in,
    const float* __restrict__ v_in, const float* __restrict__ W,
    const float* __restrict__ bias, float* __restrict__ qkv)
{
    const int m = blockIdx.z;
    const float* X  = (m == 0) ? q_in : ((m == 1) ? k_in : v_in);
    const float* Wm = W + (size_t)m * E_DIM * E_DIM;
    const float* bm = bias + m * E_DIM;
    float* out = qkv + (size_t)m * NBHTD;

    const int nBase = blockIdx.x * 128;
    const int mBase = blockIdx.y * 128;

    __shared__ float As[32][132];   // As[k][m] (transposed stage)
    __shared__ float Bs[32][132];   // Bs[k][n] = W[n][k]

    const int tid = threadIdx.x;
    const int tx = tid & 15, ty = tid >> 4;
    const int m0 = ty * 8, n0 = tx * 8;

    float acc[8][8] = {};

    for (int k0 = 0; k0 < E_DIM; k0 += 32) {
        // stage A tile: 128 rows x 32 k
        #pragma unroll
        for (int l = 0; l < 4; ++l) {
            int f = tid + 256 * l;            // float4 index 0..1023
            int row = f >> 3, c4 = f & 7;     // 8 float4 per row
            float4 v = *reinterpret_cast<const float4*>(
                &X[(size_t)(mBase + row) * E_DIM + k0 + c4 * 4]);
            As[c4 * 4 + 0][row] = v.x; As[c4 * 4 + 1][row] = v.y;
            As[c4 * 4 + 2][row] = v.z; As[c4 * 4 + 3][row] = v.w;
        }
        // stage B tile: Bs[k][n] = W[nBase+n][k0+k]
        #pragma unroll
        for (int l = 0; l < 4; ++l) {
            int f = tid + 256 * l;
            int row = f >> 3, c4 = f & 7;
            float4 v = *reinterpret_cast<const float4*>(
                &Wm[(size_t)(nBase + row) * E_DIM + k0 + c4 * 4]);
            Bs[c4 * 4 + 0][row] = v.x; Bs[c4 * 4 + 1][row] = v.y;
            Bs[c4 * 4 + 2][row] = v.z; Bs[c4 * 4 + 3][row] = v.w;
        }
        __syncthreads();

        #pragma unroll 4
        for (int k = 0; k < 32; ++k) {
            float a[8], b[8];
            *reinterpret_cast<float4*>(&a[0]) = *reinterpret_cast<const float4*>(&As[k][m0]);
            *reinterpret_cast<float4*>(&a[4]) = *reinterpret_cast<const float4*>(&As[k][m0 + 4]);
            *reinterpret_cast<float4*>(&b[0]) = *reinterpret_cast<const float4*>(&Bs[k][n0]);
            *reinterpret_cast<float4*>(&b[4]) = *reinterpret_cast<const float4*>(&Bs[k][n0 + 4]);
            #pragma unroll
            for (int i = 0; i < 8; ++i)
                #pragma unroll
                for (int j = 0; j < 8; ++j)
                    acc[i][j] += a[i] * b[j];
        }
        __syncthreads();
    }

    // epilogue: scatter into (B,H,T,D); 8 consecutive n stay within one head
    #pragma unroll
    for (int i = 0; i < 8; ++i) {
        int r = mBase + m0 + i;
        int t = r >> 1, bb = r & 1;
        int n = nBase + n0;
        int h = n >> 6, d = n & 63;
        float* dst = &out[(size_t)((bb * H_N + h) * T_SEQ + t) * D_HD + d];
        float4 w0, w1;
        w0.x = acc[i][0] + bm[n + 0]; w0.y = acc[i][1] + bm[n + 1];
        w0.z = acc[i][2] + bm[n + 2]; w0.w = acc[i][3] + bm[n + 3];
        w1.x = acc[i][4] + bm[n + 4]; w1.y = acc[i][5] + bm[n + 5];
        w1.z = acc[i][6] + bm[n + 6]; w1.w = acc[i][7] + bm[n + 7];
        *reinterpret_cast<float4*>(dst)     = w0;
        *reinterpret_cast<float4*>(dst + 4) = w1;
    }
}

// ---------------------------------------------------------------------------
// Kernel 2: per-chunk KV sums. ckv[bh][c][k][v] = sum_{s in chunk} K[s][k]*V[s][v]
// ---------------------------------------------------------------------------
__global__ __launch_bounds__(256) void k_chunkkv(
    const float* __restrict__ qkv, float* __restrict__ ckv)
{
    const float* kmat = qkv + (size_t)NBHTD;
    const float* vmat = qkv + (size_t)2 * NBHTD;
    const int c = blockIdx.x, bh = blockIdx.y;
    const int t0 = c * CHUNK;

    __shared__ float Ks[64][68];
    __shared__ float Vs[64][68];

    const int tid = threadIdx.x;
    #pragma unroll
    for (int l = 0; l < 4; ++l) {
        int f = tid + 256 * l;            // 1024 float4 per 64x64 tile
        int s = f >> 4, c4 = f & 15;
        *reinterpret_cast<float4*>(&Ks[s][c4 * 4]) = *reinterpret_cast<const float4*>(
            &kmat[((size_t)bh * T_SEQ + t0 + s) * D_HD + c4 * 4]);
        *reinterpret_cast<float4*>(&Vs[s][c4 * 4]) = *reinterpret_cast<const float4*>(
            &vmat[((size_t)bh * T_SEQ + t0 + s) * D_HD + c4 * 4]);
    }
    __syncthreads();

    const int tx = tid & 15, ty = tid >> 4;
    const int kk0 = tx * 4, vv0 = ty * 4;
    float acc[4][4] = {};
    for (int s = 0; s < 64; ++s) {
        float a[4], b[4];
        *reinterpret_cast<float4*>(a) = *reinterpret_cast<const float4*>(&Ks[s][kk0]);
        *reinterpret_cast<float4*>(b) = *reinterpret_cast<const float4*>(&Vs[s][vv0]);
        #pragma unroll
        for (int i = 0; i < 4; ++i)
            #pragma unroll
            for (int j = 0; j < 4; ++j)
                acc[i][j] += a[i] * b[j];
    }
    float* dst = ckv + ((size_t)bh * NCHUNK + c) * 4096;
    #pragma unroll
    for (int i = 0; i < 4; ++i) {
        float4 w; w.x = acc[i][0]; w.y = acc[i][1]; w.z = acc[i][2]; w.w = acc[i][3];
        *reinterpret_cast<float4*>(&dst[(kk0 + i) * 64 + vv0]) = w;
    }
}

// ---------------------------------------------------------------------------
// Kernel 3: exclusive prefix over chunks, in place. One float4 chain per thread.
// 32768 chains (32 bh x 1024 float4), 16 sequential steps each.
// ---------------------------------------------------------------------------
__global__ __launch_bounds__(256) void k_prefix(float* __restrict__ ckv)
{
    int id = blockIdx.x * blockDim.x + threadIdx.x;   // 0..32767
    int bh = id >> 10, i4 = id & 1023;
    float4 run = {0.f, 0.f, 0.f, 0.f};
    float* base = ckv + (size_t)bh * NCHUNK * 4096 + (size_t)i4 * 4;
    for (int c = 0; c < NCHUNK; ++c) {
        float4* p = reinterpret_cast<float4*>(base + (size_t)c * 4096);
        float4 v = *p;
        *p = run;
        run.x += v.x; run.y += v.y; run.z += v.z; run.w += v.w;
    }
}

// ---------------------------------------------------------------------------
// Kernel 4: per-chunk output. out = scale*( tril(Q K^T) @ V + Q @ P )
// ---------------------------------------------------------------------------
__global__ __launch_bounds__(256) void k_chunkout(
    const float* __restrict__ qkv, const float* __restrict__ ckv,
    float* __restrict__ attn)
{
    const float* qmat = qkv;
    const float* kmat = qkv + (size_t)NBHTD;
    const float* vmat = qkv + (size_t)2 * NBHTD;
    const int c = blockIdx.x, bh = blockIdx.y;
    const int t0 = c * CHUNK;

    __shared__ float Qs[64][68];
    __shared__ float Ks[64][68];   // later reused for P, then Qs reused for V
    __shared__ float Ss[64][68];

    const int tid = threadIdx.x;
    const int tx = tid & 15, ty = tid >> 4;

    #pragma unroll
    for (int l = 0; l < 4; ++l) {
        int f = tid + 256 * l;
        int s = f >> 4, c4 = f & 15;
        *reinterpret_cast<float4*>(&Qs[s][c4 * 4]) = *reinterpret_cast<const float4*>(
            &qmat[((size_t)bh * T_SEQ + t0 + s) * D_HD + c4 * 4]);
        *reinterpret_cast<float4*>(&Ks[s][c4 * 4]) = *reinterpret_cast<const float4*>(
            &kmat[((size_t)bh * T_SEQ + t0 + s) * D_HD + c4 * 4]);
    }
    __syncthreads();

    // S = tril(Q K^T), inclusive diagonal
    const int tq0 = ty * 4, tk0 = tx * 4;
    {
        float sacc[4][4] = {};
        for (int k = 0; k < 64; ++k) {
            float qa[4], kb[4];
            #pragma unroll
            for (int i = 0; i < 4; ++i) qa[i] = Qs[tq0 + i][k];
            #pragma unroll
            for (int j = 0; j < 4; ++j) kb[j] = Ks[tk0 + j][k];
            #pragma unroll
            for (int i = 0; i < 4; ++i)
                #pragma unroll
                for (int j = 0; j < 4; ++j)
                    sacc[i][j] += qa[i] * kb[j];
        }
        #pragma unroll
        for (int i = 0; i < 4; ++i)
            #pragma unroll
            for (int j = 0; j < 4; ++j)
                Ss[tq0 + i][tk0 + j] = (tk0 + j <= tq0 + i) ? sacc[i][j] : 0.f;
    }
    __syncthreads();

    // stage P (exclusive prefix KV) into Ks
    const float* P = ckv + ((size_t)bh * NCHUNK + c) * 4096;
    #pragma unroll
    for (int l = 0; l < 4; ++l) {
        int f = tid + 256 * l;
        int s = f >> 4, c4 = f & 15;
        *reinterpret_cast<float4*>(&Ks[s][c4 * 4]) =
            *reinterpret_cast<const float4*>(&P[s * 64 + c4 * 4]);
    }
    __syncthreads();

    // acc = Q @ P
    const int v0 = tx * 4;
    float oacc[4][4] = {};
    for (int k = 0; k < 64; ++k) {
        float qa[4], pb[4];
        #pragma unroll
        for (int i = 0; i < 4; ++i) qa[i] = Qs[tq0 + i][k];
        *reinterpret_cast<float4*>(pb) = *reinterpret_cast<const float4*>(&Ks[k][v0]);
        #pragma unroll
        for (int i = 0; i < 4; ++i)
            #pragma unroll
            for (int j = 0; j < 4; ++j)
                oacc[i][j] += qa[i] * pb[j];
    }
    __syncthreads();

    // stage V into Qs
    #pragma unroll
    for (int l = 0; l < 4; ++l) {
        int f = tid + 256 * l;
        int s = f >> 4, c4 = f & 15;
        *reinterpret_cast<float4*>(&Qs[s][c4 * 4]) = *reinterpret_cast<const float4*>(
            &vmat[((size_t)bh * T_SEQ + t0 + s) * D_HD + c4 * 4]);
    }
    __syncthreads();

    // acc += S @ V
    for (int s = 0; s < 64; ++s) {
        float sa[4], vb[4];
        #pragma unroll
        for (int i = 0; i < 4; ++i) sa[i] = Ss[tq0 + i][s];
        *reinterpret_cast<float4*>(vb) = *reinterpret_cast<const float4*>(&Qs[s][v0]);
        #pragma unroll
        for (int i = 0; i < 4; ++i)
            #pragma unroll
            for (int j = 0; j < 4; ++j)
                oacc[i][j] += sa[i] * vb[j];
    }

    const float scale = 0.125f;   // 1/sqrt(D)
    #pragma unroll
    for (int i = 0; i < 4; ++i) {
        float4 w;
        w.x = oacc[i][0] * scale; w.y = oacc[i][1] * scale;
        w.z = oacc[i][2] * scale; w.w = oacc[i][3] * scale;
        *reinterpret_cast<float4*>(
            &attn[((size_t)bh * T_SEQ + t0 + tq0 + i) * D_HD + v0]) = w;
    }
}

// ---------------------------------------------------------------------------
// Kernel 5: out-projection. out[(t*B+b)*E + e] = sum_c attn[b][h(c)][t][d(c)]*Wo[e][c] + bo[e]
// Same 128x128 tile structure as k_inproj; A gathered from (B,H,T,D).
// ---------------------------------------------------------------------------
__global__ __launch_bounds__(256) void k_outproj(
    const float* __restrict__ attn, const float* __restrict__ W,
    const float* __restrict__ bias, float* __restrict__ out)
{
    const int nBase = blockIdx.x * 128;
    const int mBase = blockIdx.y * 128;

    __shared__ float As[32][132];
    __shared__ float Bs[32][132];

    const int tid = threadIdx.x;
    const int tx = tid & 15, ty = tid >> 4;
    const int m0 = ty * 8, n0 = tx * 8;

    float acc[8][8] = {};

    for (int k0 = 0; k0 < E_DIM; k0 += 32) {
        const int hh = k0 >> 6;          // constant within a 32-wide k tile
        const int dbase = k0 & 63;
        #pragma unroll
        for (int l = 0; l < 4; ++l) {
            int f = tid + 256 * l;
            int row = f >> 3, c4 = f & 7;
            int r = mBase + row;
            int t = r >> 1, bb = r & 1;
            float4 v = *reinterpret_cast<const float4*>(
                &attn[((size_t)(bb * H_N + hh) * T_SEQ + t) * D_HD + dbase + c4 * 4]);
            As[c4 * 4 + 0][row] = v.x; As[c4 * 4 + 1][row] = v.y;
            As[c4 * 4 + 2][row] = v.z; As[c4 * 4 + 3][row] = v.w;
        }
        #pragma unroll
        for (int l = 0; l < 4; ++l) {
            int f = tid + 256 * l;
            int row = f >> 3, c4 = f & 7;
            float4 v = *reinterpret_cast<const float4*>(
                &W[(size_t)(nBase + row) * E_DIM + k0 + c4 * 4]);
            Bs[c4 * 4 + 0][row] = v.x; Bs[c4 * 4 + 1][row] = v.y;
            Bs[c4 * 4 + 2][row] = v.z; Bs[c4 * 4 + 3][row] = v.w;
        }
        __syncthreads();

        #pragma unroll 4
        for (int k = 0; k < 32; ++k) {
            float a[8], b[8];
            *reinterpret_cast<float4*>(&a[0]) = *reinterpret_cast<const float4*>(&As[k][m0]);
            *reinterpret_cast<float4*>(&a[4]) = *reinterpret_cast<const float4*>(&As[k][m0 + 4]);
            *reinterpret_cast<float4*>(&b[0]) = *reinterpret_cast<const float4*>(&Bs[k][n0]);
            *reinterpret_cast<float4*>(&b[4]) = *reinterpret_cast<const float4*>(&Bs[k][n0 + 4]);
            #pragma unroll
            for (int i = 0; i < 8; ++i)
                #pragma unroll
                for (int j = 0; j < 8; ++j)
                    acc[i][j] += a[i] * b[j];
        }
        __syncthreads();
    }

    #pragma unroll
    for (int i = 0; i < 8; ++i) {
        int r = mBase + m0 + i;
        int n = nBase + n0;
        float* dst = &out[(size_t)r * E_DIM + n];
        float4 w0, w1;
        w0.x = acc[i][0] + bias[n + 0]; w0.y = acc[i][1] + bias[n + 1];
        w0.z = acc[i][2] + bias[n + 2]; w0.w = acc[i][3] + bias[n + 3];
        w1.x = acc[i][4] + bias[n + 4]; w1.y = acc[i][5] + bias[n + 5];
        w1.z = acc[i][6] + bias[n + 6]; w1.w = acc[i][7] + bias[n + 7];
        *reinterpret_cast<float4*>(dst)     = w0;
        *reinterpret_cast<float4*>(dst + 4) = w1;
    }
}

// ---------------------------------------------------------------------------
extern "C" void kernel_launch(void* const* d_in, const int* in_sizes, int n_in,
                              void* d_out, int out_size, void* d_ws, size_t ws_size,
                              hipStream_t stream)
{
    const float* q_in  = (const float*)d_in[0];
    const float* k_in  = (const float*)d_in[1];
    const float* v_in  = (const float*)d_in[2];
    const float* w_in  = (const float*)d_in[3];
    const float* b_in  = (const float*)d_in[4];
    const float* w_out = (const float*)d_in[5];
    const float* b_out = (const float*)d_in[6];

    float* ws   = (float*)d_ws;
    float* qkv  = ws;                               // 3 * 2,097,152 floats
    float* ckv  = ws + (size_t)3 * NBHTD;           // 2,097,152 floats
    float* attn = ws + (size_t)3 * NBHTD + (size_t)BH * NCHUNK * 4096; // 2,097,152
    float* outp = (float*)d_out;

    // 1. in-projection -> q,k,v in (B,H,T,D)
    k_inproj<<<dim3(E_DIM / 128, NROWS / 128, 3), 256, 0, stream>>>(
        q_in, k_in, v_in, w_in, b_in, qkv);
    // 2. per-chunk KV outer-product sums
    k_chunkkv<<<dim3(NCHUNK, BH), 256, 0, stream>>>(qkv, ckv);
    // 3. exclusive prefix over chunks (in place)
    k_prefix<<<dim3(BH * 1024 / 256), 256, 0, stream>>>(ckv);
    // 4. per-chunk attention output
    k_chunkout<<<dim3(NCHUNK, BH), 256, 0, stream>>>(qkv, ckv, attn);
    // 5. out-projection -> (T,B,E)
    k_outproj<<<dim3(E_DIM / 128, NROWS / 128), 256, 0, stream>>>(
        attn, w_out, b_out, outp);
}

// Round 3
// 177.622 us; speedup vs baseline: 3.0115x; 3.0115x over previous
//
#include <hip/hip_runtime.h>

// Round 2: bf16 MFMA for in-proj and out-proj GEMMs (m97 structure:
// 128x128 tile, BK=64, 4 waves, global_load_lds w=16). Attention chunk
// pipeline stays fp32; attn intermediate stored bf16 for the out-proj GEMM.

#define T_SEQ 1024
#define B_SZ  2
#define E_DIM 1024
#define H_N   16
#define D_HD  64
#define NROWS (T_SEQ * B_SZ)          // 2048
#define CHUNK 64
#define NCHUNK (T_SEQ / CHUNK)        // 16
#define BH (B_SZ * H_N)               // 32
#define NBHTD (NROWS * E_DIM)         // 2,097,152 elements per q/k/v slab

typedef short bf16x8 __attribute__((ext_vector_type(8)));
typedef float f32x4  __attribute__((ext_vector_type(4)));

__device__ inline unsigned short f2bf(float f) {
    unsigned u = __builtin_bit_cast(unsigned, f);
    u = (u + 0x7FFFu + ((u >> 16) & 1u)) >> 16;   // RNE; inputs finite
    return (unsigned short)u;
}

__device__ inline void gload_lds16(const void* g, void* l) {
    __builtin_amdgcn_global_load_lds(
        (const __attribute__((address_space(1))) unsigned int*)g,
        (__attribute__((address_space(3))) unsigned int*)l, 16, 0, 0);
}

// ---------------------------------------------------------------------------
// Kernel 0: cast weights fp32 -> bf16. Wi (3M) then Wo (1M), contiguous dst.
// ---------------------------------------------------------------------------
__global__ __launch_bounds__(256) void k_castw(
    const float* __restrict__ w_in, const float* __restrict__ w_out,
    unsigned short* __restrict__ dst)
{
    const int id8 = blockIdx.x * 256 + threadIdx.x;   // float8 unit, 524288 total
    const int WI8 = 3 * E_DIM * E_DIM / 8;            // 393216
    const float* src = (id8 < WI8) ? (w_in + (size_t)id8 * 8)
                                   : (w_out + (size_t)(id8 - WI8) * 8);
    float4 f0 = *reinterpret_cast<const float4*>(src);
    float4 f1 = *reinterpret_cast<const float4*>(src + 4);
    ushort4 o0, o1;
    o0.x = f2bf(f0.x); o0.y = f2bf(f0.y); o0.z = f2bf(f0.z); o0.w = f2bf(f0.w);
    o1.x = f2bf(f1.x); o1.y = f2bf(f1.y); o1.z = f2bf(f1.z); o1.w = f2bf(f1.w);
    *reinterpret_cast<ushort4*>(dst + (size_t)id8 * 8)     = o0;
    *reinterpret_cast<ushort4*>(dst + (size_t)id8 * 8 + 4) = o1;
}

// ---------------------------------------------------------------------------
// GEMM: C[2048x1024] = A[2048x1024] @ W[1024x1024]^T + bias, fp32 out.
// AF32: A is fp32 (reg-stage + convert into padded LDS). Else A is bf16
// (global_load_lds, linear LDS). W always bf16 via global_load_lds.
// blockIdx.z selects among 3 A/W/bias/C slabs (in-proj); z-grid=1 for out-proj.
// ---------------------------------------------------------------------------
template<bool AF32>
__global__ __launch_bounds__(256) void k_gemm(
    const float* __restrict__ A0, const float* __restrict__ A1,
    const float* __restrict__ A2, const unsigned short* __restrict__ Abf,
    const unsigned short* __restrict__ Wbf, const float* __restrict__ bias,
    float* __restrict__ C)
{
    constexpr int K = E_DIM, N = E_DIM;
    constexpr int LDA = AF32 ? 72 : 64;           // shorts per row
    const int z = blockIdx.z;
    const int nBase = blockIdx.x * 128;
    const int mBase = blockIdx.y * 128;
    const unsigned short* W = Wbf + (size_t)z * K * N;
    const float* bz = bias + (size_t)z * N;
    float* Cz = C + (size_t)z * NROWS * N;
    const float* Af = (z == 0) ? A0 : (z == 1 ? A1 : A2);

    __shared__ short As[128 * LDA];
    __shared__ short Bs[128 * 64];

    const int tid = threadIdx.x;
    const int lane = tid & 63, wave = tid >> 6;
    const int wr = wave >> 1, wc = wave & 1;      // 2x2 wave grid, 64x64 each
    const int l15 = lane & 15, l4 = lane >> 4;

    f32x4 acc[4][4] = {};

    for (int k0 = 0; k0 < K; k0 += 64) {
        // stage B (weights, bf16): 128 rows x 64 k = 16KB, linear LDS
        #pragma unroll
        for (int l = 0; l < 4; ++l) {
            int off = l * 4096 + tid * 16;        // byte offset
            int row = off >> 7, kb = off & 127;
            gload_lds16((const char*)W + ((size_t)(nBase + row) * K + k0) * 2 + kb,
                        (char*)Bs + off);
        }
        if constexpr (AF32) {
            // reg-stage A fp32 -> bf16, padded LDS (LDA=72)
            #pragma unroll
            for (int l = 0; l < 4; ++l) {
                int u = tid + 256 * l;            // bf16x8 unit, 1024 total
                int row = u >> 3, ko = (u & 7) * 8;
                const float* src = &Af[(size_t)(mBase + row) * K + k0 + ko];
                float4 f0 = *reinterpret_cast<const float4*>(src);
                float4 f1 = *reinterpret_cast<const float4*>(src + 4);
                bf16x8 p;
                p[0] = (short)f2bf(f0.x); p[1] = (short)f2bf(f0.y);
                p[2] = (short)f2bf(f0.z); p[3] = (short)f2bf(f0.w);
                p[4] = (short)f2bf(f1.x); p[5] = (short)f2bf(f1.y);
                p[6] = (short)f2bf(f1.z); p[7] = (short)f2bf(f1.w);
                *reinterpret_cast<bf16x8*>(&As[row * LDA + ko]) = p;
            }
        } else {
            #pragma unroll
            for (int l = 0; l < 4; ++l) {
                int off = l * 4096 + tid * 16;
                int row = off >> 7, kb = off & 127;
                gload_lds16((const char*)Abf + ((size_t)(mBase + row) * K + k0) * 2 + kb,
                            (char*)As + off);
            }
        }
        __syncthreads();

        #pragma unroll
        for (int kk = 0; kk < 64; kk += 32) {
            bf16x8 af[4], bfr[4];
            #pragma unroll
            for (int i = 0; i < 4; ++i) {
                af[i]  = *reinterpret_cast<const bf16x8*>(
                             &As[(wr * 64 + i * 16 + l15) * LDA + kk + l4 * 8]);
                bfr[i] = *reinterpret_cast<const bf16x8*>(
                             &Bs[(wc * 64 + i * 16 + l15) * 64 + kk + l4 * 8]);
            }
            #pragma unroll
            for (int i = 0; i < 4; ++i)
                #pragma unroll
                for (int j = 0; j < 4; ++j)
                    acc[i][j] = __builtin_amdgcn_mfma_f32_16x16x32_bf16(
                        af[i], bfr[j], acc[i][j], 0, 0, 0);
        }
        __syncthreads();
    }

    // epilogue: C/D layout col=lane&15, row=(lane>>4)*4+reg
    #pragma unroll
    for (int i = 0; i < 4; ++i) {
        int row0 = mBase + wr * 64 + i * 16 + l4 * 4;
        #pragma unroll
        for (int j = 0; j < 4; ++j) {
            int col = nBase + wc * 64 + j * 16 + l15;
            float bv = bz[col];
            #pragma unroll
            for (int q = 0; q < 4; ++q)
                Cz[(size_t)(row0 + q) * N + col] = acc[i][j][q] + bv;
        }
    }
}

// ---------------------------------------------------------------------------
// Kernel 2: per-chunk KV sums from row-major fp32 k/v slabs.
// ckv[bh][c][k][v] = sum_{s in chunk} K[s][k]*V[s][v]
// ---------------------------------------------------------------------------
__global__ __launch_bounds__(256) void k_chunkkv(
    const float* __restrict__ kslab, const float* __restrict__ vslab,
    float* __restrict__ ckv)
{
    const int c = blockIdx.x, bh = blockIdx.y;
    const int b = bh >> 4, h = bh & 15;
    const int colb = h * 64;
    const int t0 = c * CHUNK;

    __shared__ float Ks[64][68];
    __shared__ float Vs[64][68];

    const int tid = threadIdx.x;
    #pragma unroll
    for (int l = 0; l < 4; ++l) {
        int f = tid + 256 * l;
        int s = f >> 4, c4 = f & 15;
        size_t r = (size_t)((t0 + s) * 2 + b) * E_DIM + colb + c4 * 4;
        *reinterpret_cast<float4*>(&Ks[s][c4 * 4]) = *reinterpret_cast<const float4*>(&kslab[r]);
        *reinterpret_cast<float4*>(&Vs[s][c4 * 4]) = *reinterpret_cast<const float4*>(&vslab[r]);
    }
    __syncthreads();

    const int tx = tid & 15, ty = tid >> 4;
    const int kk0 = tx * 4, vv0 = ty * 4;
    float acc[4][4] = {};
    for (int s = 0; s < 64; ++s) {
        float a[4], bb[4];
        *reinterpret_cast<float4*>(a)  = *reinterpret_cast<const float4*>(&Ks[s][kk0]);
        *reinterpret_cast<float4*>(bb) = *reinterpret_cast<const float4*>(&Vs[s][vv0]);
        #pragma unroll
        for (int i = 0; i < 4; ++i)
            #pragma unroll
            for (int j = 0; j < 4; ++j)
                acc[i][j] += a[i] * bb[j];
    }
    float* dst = ckv + ((size_t)bh * NCHUNK + c) * 4096;
    #pragma unroll
    for (int i = 0; i < 4; ++i) {
        float4 w; w.x = acc[i][0]; w.y = acc[i][1]; w.z = acc[i][2]; w.w = acc[i][3];
        *reinterpret_cast<float4*>(&dst[(kk0 + i) * 64 + vv0]) = w;
    }
}

// ---------------------------------------------------------------------------
// Kernel 3: exclusive prefix over chunks, in place.
// ---------------------------------------------------------------------------
__global__ __launch_bounds__(256) void k_prefix(float* __restrict__ ckv)
{
    int id = blockIdx.x * blockDim.x + threadIdx.x;   // 0..32767
    int bh = id >> 10, i4 = id & 1023;
    float4 run = {0.f, 0.f, 0.f, 0.f};
    float* base = ckv + (size_t)bh * NCHUNK * 4096 + (size_t)i4 * 4;
    for (int c = 0; c < NCHUNK; ++c) {
        float4* p = reinterpret_cast<float4*>(base + (size_t)c * 4096);
        float4 v = *p;
        *p = run;
        run.x += v.x; run.y += v.y; run.z += v.z; run.w += v.w;
    }
}

// ---------------------------------------------------------------------------
// Kernel 4: per-chunk output, fp32 math; writes attn as bf16 row-major.
// out = scale*( tril(Q K^T) @ V + Q @ P )
// ---------------------------------------------------------------------------
__global__ __launch_bounds__(256) void k_chunkout(
    const float* __restrict__ qslab, const float* __restrict__ kslab,
    const float* __restrict__ vslab, const float* __restrict__ ckv,
    unsigned short* __restrict__ attnbf)
{
    const int c = blockIdx.x, bh = blockIdx.y;
    const int b = bh >> 4, h = bh & 15;
    const int colb = h * 64;
    const int t0 = c * CHUNK;

    __shared__ float Qs[64][68];
    __shared__ float Ks[64][68];
    __shared__ float Ss[64][68];

    const int tid = threadIdx.x;
    const int tx = tid & 15, ty = tid >> 4;

    #pragma unroll
    for (int l = 0; l < 4; ++l) {
        int f = tid + 256 * l;
        int s = f >> 4, c4 = f & 15;
        size_t r = (size_t)((t0 + s) * 2 + b) * E_DIM + colb + c4 * 4;
        *reinterpret_cast<float4*>(&Qs[s][c4 * 4]) = *reinterpret_cast<const float4*>(&qslab[r]);
        *reinterpret_cast<float4*>(&Ks[s][c4 * 4]) = *reinterpret_cast<const float4*>(&kslab[r]);
    }
    __syncthreads();

    const int tq0 = ty * 4, tk0 = tx * 4;
    {
        float sacc[4][4] = {};
        for (int k = 0; k < 64; ++k) {
            float qa[4], kb[4];
            #pragma unroll
            for (int i = 0; i < 4; ++i) qa[i] = Qs[tq0 + i][k];
            #pragma unroll
            for (int j = 0; j < 4; ++j) kb[j] = Ks[tk0 + j][k];
            #pragma unroll
            for (int i = 0; i < 4; ++i)
                #pragma unroll
                for (int j = 0; j < 4; ++j)
                    sacc[i][j] += qa[i] * kb[j];
        }
        #pragma unroll
        for (int i = 0; i < 4; ++i)
            #pragma unroll
            for (int j = 0; j < 4; ++j)
                Ss[tq0 + i][tk0 + j] = (tk0 + j <= tq0 + i) ? sacc[i][j] : 0.f;
    }
    __syncthreads();

    // stage P (exclusive prefix) into Ks
    const float* P = ckv + ((size_t)bh * NCHUNK + c) * 4096;
    #pragma unroll
    for (int l = 0; l < 4; ++l) {
        int f = tid + 256 * l;
        int s = f >> 4, c4 = f & 15;
        *reinterpret_cast<float4*>(&Ks[s][c4 * 4]) =
            *reinterpret_cast<const float4*>(&P[s * 64 + c4 * 4]);
    }
    __syncthreads();

    const int v0 = tx * 4;
    float oacc[4][4] = {};
    for (int k = 0; k < 64; ++k) {
        float qa[4], pb[4];
        #pragma unroll
        for (int i = 0; i < 4; ++i) qa[i] = Qs[tq0 + i][k];
        *reinterpret_cast<float4*>(pb) = *reinterpret_cast<const float4*>(&Ks[k][v0]);
        #pragma unroll
        for (int i = 0; i < 4; ++i)
            #pragma unroll
            for (int j = 0; j < 4; ++j)
                oacc[i][j] += qa[i] * pb[j];
    }
    __syncthreads();

    // stage V into Qs
    #pragma unroll
    for (int l = 0; l < 4; ++l) {
        int f = tid + 256 * l;
        int s = f >> 4, c4 = f & 15;
        size_t r = (size_t)((t0 + s) * 2 + b) * E_DIM + colb + c4 * 4;
        *reinterpret_cast<float4*>(&Qs[s][c4 * 4]) = *reinterpret_cast<const float4*>(&vslab[r]);
    }
    __syncthreads();

    for (int s = 0; s < 64; ++s) {
        float sa[4], vb[4];
        #pragma unroll
        for (int i = 0; i < 4; ++i) sa[i] = Ss[tq0 + i][s];
        *reinterpret_cast<float4*>(vb) = *reinterpret_cast<const float4*>(&Qs[s][v0]);
        #pragma unroll
        for (int i = 0; i < 4; ++i)
            #pragma unroll
            for (int j = 0; j < 4; ++j)
                oacc[i][j] += sa[i] * vb[j];
    }

    const float scale = 0.125f;
    #pragma unroll
    for (int i = 0; i < 4; ++i) {
        int r = (t0 + tq0 + i) * 2 + b;
        ushort4 w;
        w.x = f2bf(oacc[i][0] * scale); w.y = f2bf(oacc[i][1] * scale);
        w.z = f2bf(oacc[i][2] * scale); w.w = f2bf(oacc[i][3] * scale);
        *reinterpret_cast<ushort4*>(&attnbf[(size_t)r * E_DIM + colb + v0]) = w;
    }
}

// ---------------------------------------------------------------------------
extern "C" void kernel_launch(void* const* d_in, const int* in_sizes, int n_in,
                              void* d_out, int out_size, void* d_ws, size_t ws_size,
                              hipStream_t stream)
{
    const float* q_in  = (const float*)d_in[0];
    const float* k_in  = (const float*)d_in[1];
    const float* v_in  = (const float*)d_in[2];
    const float* w_in  = (const float*)d_in[3];
    const float* b_in  = (const float*)d_in[4];
    const float* w_out = (const float*)d_in[5];
    const float* b_out = (const float*)d_in[6];

    // ws layout (40 MiB total):
    //   [0,  6 MiB)  Wibf  (3M bf16)  -- later aliased by attnbf (4 MiB)
    //   [6,  8 MiB)  Wobf  (1M bf16)
    //   [8, 32 MiB)  q/k/v fp32 slabs (3 x 2M floats, row-major [2048][1024])
    //   [32,40 MiB)  ckv   (2M floats)
    char* w = (char*)d_ws;
    unsigned short* Wibf = (unsigned short*)w;
    unsigned short* Wbf_all = Wibf;                       // Wi then Wo contiguous
    float* qslab = (float*)(w + 8388608);
    float* kslab = qslab + NBHTD;
    float* vslab = kslab + NBHTD;
    float* ckv   = (float*)(w + 8388608 + 3 * (size_t)NBHTD * 4);
    unsigned short* Wobf = (unsigned short*)(w + 6291456);
    unsigned short* attnbf = (unsigned short*)w;          // aliases Wibf (dead)
    float* outp = (float*)d_out;

    // 0. cast weights to bf16 (4M elements, 524288 float8 units)
    k_castw<<<2048, 256, 0, stream>>>(w_in, w_out, Wbf_all);

    // 1. in-projection (bf16 MFMA), z selects q/k/v
    k_gemm<true><<<dim3(8, 16, 3), 256, 0, stream>>>(
        q_in, k_in, v_in, nullptr, Wibf, b_in, qslab);

    // 2-4. chunked linear attention (fp32), attn written bf16
    k_chunkkv<<<dim3(NCHUNK, BH), 256, 0, stream>>>(kslab, vslab, ckv);
    k_prefix<<<dim3(BH * 1024 / 256), 256, 0, stream>>>(ckv);
    k_chunkout<<<dim3(NCHUNK, BH), 256, 0, stream>>>(qslab, kslab, vslab, ckv, attnbf);

    // 5. out-projection (bf16 MFMA) -> (T,B,E) fp32
    k_gemm<false><<<dim3(8, 16, 1), 256, 0, stream>>>(
        nullptr, nullptr, nullptr, attnbf, Wobf, b_out, outp);
}

// Round 4
// 155.409 us; speedup vs baseline: 3.4419x; 1.1429x over previous
//
#include <hip/hip_runtime.h>

// Round 3: all-MFMA pipeline. 64x128 GEMM tiles (more blocks/CU), bf16
// b-major slabs with pre-transposed Kt/Vt written by the in-proj epilogue,
// MFMA chunk-KV (stored as ckv^T) and MFMA chunk-out (QK^T -> mask -> SV+QP).

#define T_SEQ 1024
#define B_SZ  2
#define E_DIM 1024
#define H_N   16
#define D_HD  64
#define NROWS (T_SEQ * B_SZ)          // 2048
#define CHUNK 64
#define NCHUNK (T_SEQ / CHUNK)        // 16
#define BH (B_SZ * H_N)               // 32

typedef short bf16x8 __attribute__((ext_vector_type(8)));
typedef float f32x4  __attribute__((ext_vector_type(4)));

__device__ inline unsigned short f2bf(float f) {
    unsigned u = __builtin_bit_cast(unsigned, f);
    u = (u + 0x7FFFu + ((u >> 16) & 1u)) >> 16;   // RNE; inputs finite
    return (unsigned short)u;
}

__device__ inline void gload_lds16(const void* g, void* l) {
    __builtin_amdgcn_global_load_lds(
        (const __attribute__((address_space(1))) unsigned int*)g,
        (__attribute__((address_space(3))) unsigned int*)l, 16, 0, 0);
}

// ---------------------------------------------------------------------------
// Kernel 0: cast weights fp32 -> bf16. Wi (3M) then Wo (1M), contiguous dst.
// ---------------------------------------------------------------------------
__global__ __launch_bounds__(256) void k_castw(
    const float* __restrict__ w_in, const float* __restrict__ w_out,
    unsigned short* __restrict__ dst)
{
    const int id8 = blockIdx.x * 256 + threadIdx.x;   // float8 unit, 524288 total
    const int WI8 = 3 * E_DIM * E_DIM / 8;            // 393216
    const float* src = (id8 < WI8) ? (w_in + (size_t)id8 * 8)
                                   : (w_out + (size_t)(id8 - WI8) * 8);
    float4 f0 = *reinterpret_cast<const float4*>(src);
    float4 f1 = *reinterpret_cast<const float4*>(src + 4);
    ushort4 o0, o1;
    o0.x = f2bf(f0.x); o0.y = f2bf(f0.y); o0.z = f2bf(f0.z); o0.w = f2bf(f0.w);
    o1.x = f2bf(f1.x); o1.y = f2bf(f1.y); o1.z = f2bf(f1.z); o1.w = f2bf(f1.w);
    *reinterpret_cast<ushort4*>(dst + (size_t)id8 * 8)     = o0;
    *reinterpret_cast<ushort4*>(dst + (size_t)id8 * 8 + 4) = o1;
}

// ---------------------------------------------------------------------------
// Kernel 1: in-projection GEMM, 64x128 tile, BK=64, 4 waves (2x2, 32x64 each).
// A fp32 reg-staged->bf16 (padded LDS); W bf16 via global_load_lds.
// M-rows are b-major (r' = b*1024 + t), so a 64-row tile has uniform b.
// Epilogue: z=0 -> Q natural [b][t][e]; z=1 -> K natural AND Kt [b][e][t];
//           z=2 -> Vt [b][e][t] only. All bf16.
// ---------------------------------------------------------------------------
__global__ __launch_bounds__(256) void k_gin(
    const float* __restrict__ q_in, const float* __restrict__ k_in,
    const float* __restrict__ v_in, const unsigned short* __restrict__ Wibf,
    const float* __restrict__ b_in,
    unsigned short* __restrict__ qslab, unsigned short* __restrict__ kslab,
    unsigned short* __restrict__ ktb,   unsigned short* __restrict__ vtb)
{
    const int z = blockIdx.z;
    const float* X = (z == 0) ? q_in : (z == 1 ? k_in : v_in);
    const unsigned short* W = Wibf + (size_t)z * E_DIM * E_DIM;
    const float* bz = b_in + z * E_DIM;

    const int nBase = blockIdx.x * 128;
    const int mBase = blockIdx.y * 64;        // b-major row space
    const int b = mBase >> 10;
    const int tBase = mBase & 1023;

    __shared__ short As[64 * 72];             // padded
    __shared__ short Bs[128 * 64];            // linear (gload_lds)

    const int tid = threadIdx.x;
    const int lane = tid & 63, wave = tid >> 6;
    const int wr = wave >> 1, wc = wave & 1;
    const int l15 = lane & 15, l4 = lane >> 4;

    f32x4 acc[2][4] = {};

    for (int k0 = 0; k0 < E_DIM; k0 += 64) {
        #pragma unroll
        for (int l = 0; l < 4; ++l) {         // B: 128x64 bf16 = 16KB
            int off = l * 4096 + tid * 16;
            int row = off >> 7, kb = off & 127;
            gload_lds16((const char*)W + ((size_t)(nBase + row) * E_DIM + k0) * 2 + kb,
                        (char*)Bs + off);
        }
        #pragma unroll
        for (int l = 0; l < 2; ++l) {         // A: 64x64 fp32 -> bf16
            int u = tid + 256 * l;
            int row = u >> 3, ko = (u & 7) * 8;
            const float* src = &X[(size_t)((tBase + row) * 2 + b) * E_DIM + k0 + ko];
            float4 f0 = *reinterpret_cast<const float4*>(src);
            float4 f1 = *reinterpret_cast<const float4*>(src + 4);
            bf16x8 p;
            p[0] = (short)f2bf(f0.x); p[1] = (short)f2bf(f0.y);
            p[2] = (short)f2bf(f0.z); p[3] = (short)f2bf(f0.w);
            p[4] = (short)f2bf(f1.x); p[5] = (short)f2bf(f1.y);
            p[6] = (short)f2bf(f1.z); p[7] = (short)f2bf(f1.w);
            *reinterpret_cast<bf16x8*>(&As[row * 72 + ko]) = p;
        }
        __syncthreads();

        #pragma unroll
        for (int kk = 0; kk < 64; kk += 32) {
            bf16x8 af[2], bfr[4];
            #pragma unroll
            for (int i = 0; i < 2; ++i)
                af[i] = *reinterpret_cast<const bf16x8*>(
                            &As[(wr * 32 + i * 16 + l15) * 72 + kk + l4 * 8]);
            #pragma unroll
            for (int j = 0; j < 4; ++j)
                bfr[j] = *reinterpret_cast<const bf16x8*>(
                            &Bs[(wc * 64 + j * 16 + l15) * 64 + kk + l4 * 8]);
            #pragma unroll
            for (int i = 0; i < 2; ++i)
                #pragma unroll
                for (int j = 0; j < 4; ++j)
                    acc[i][j] = __builtin_amdgcn_mfma_f32_16x16x32_bf16(
                        af[i], bfr[j], acc[i][j], 0, 0, 0);
        }
        __syncthreads();
    }

    // epilogue
    #pragma unroll
    for (int i = 0; i < 2; ++i) {
        int t0 = tBase + wr * 32 + i * 16 + l4 * 4;
        #pragma unroll
        for (int j = 0; j < 4; ++j) {
            int col = nBase + wc * 64 + j * 16 + l15;
            float bv = bz[col];
            unsigned short v4[4];
            #pragma unroll
            for (int q = 0; q < 4; ++q) v4[q] = f2bf(acc[i][j][q] + bv);
            if (z == 0) {
                #pragma unroll
                for (int q = 0; q < 4; ++q)
                    qslab[(size_t)b * 1048576 + (size_t)(t0 + q) * E_DIM + col] = v4[q];
            } else if (z == 1) {
                #pragma unroll
                for (int q = 0; q < 4; ++q)
                    kslab[(size_t)b * 1048576 + (size_t)(t0 + q) * E_DIM + col] = v4[q];
                ushort4 w = {v4[0], v4[1], v4[2], v4[3]};
                *reinterpret_cast<ushort4*>(
                    &ktb[((size_t)b * 1024 + col) * 1024 + t0]) = w;
            } else {
                ushort4 w = {v4[0], v4[1], v4[2], v4[3]};
                *reinterpret_cast<ushort4*>(
                    &vtb[((size_t)b * 1024 + col) * 1024 + t0]) = w;
            }
        }
    }
}

// ---------------------------------------------------------------------------
// Kernel 2: per-chunk KV sums (MFMA). ckvT[bh][c][dv][dk] = sum_s V[s,dv]K[s,dk]
// A = Vt rows, B = Kt rows (both natural, gload_lds). fp32 output.
// ---------------------------------------------------------------------------
__global__ __launch_bounds__(256) void k_chunkkv(
    const unsigned short* __restrict__ ktb, const unsigned short* __restrict__ vtb,
    float* __restrict__ ckvT)
{
    const int c = blockIdx.x, bh = blockIdx.y;
    const int b = bh >> 4, h = bh & 15;
    const int colb = h * 64, t0 = c * CHUNK;

    __shared__ short Avs[64 * 64];
    __shared__ short Bks[64 * 64];

    const int tid = threadIdx.x;
    const int lane = tid & 63, wave = tid >> 6;
    const int wr = wave >> 1, wc = wave & 1;
    const int l15 = lane & 15, l4 = lane >> 4;

    #pragma unroll
    for (int l = 0; l < 2; ++l) {
        int off = l * 4096 + tid * 16;
        int row = off >> 7, kb = off & 127;
        size_t rbase = ((size_t)(b * 1024 + colb + row)) * 1024 + t0;
        gload_lds16((const char*)vtb + rbase * 2 + kb, (char*)Avs + off);
        gload_lds16((const char*)ktb + rbase * 2 + kb, (char*)Bks + off);
    }
    __syncthreads();

    f32x4 acc[2][2] = {};
    #pragma unroll
    for (int kk = 0; kk < 64; kk += 32) {
        bf16x8 af[2], bfr[2];
        #pragma unroll
        for (int i = 0; i < 2; ++i)
            af[i] = *reinterpret_cast<const bf16x8*>(
                        &Avs[(wr * 32 + i * 16 + l15) * 64 + kk + l4 * 8]);
        #pragma unroll
        for (int j = 0; j < 2; ++j)
            bfr[j] = *reinterpret_cast<const bf16x8*>(
                        &Bks[(wc * 32 + j * 16 + l15) * 64 + kk + l4 * 8]);
        #pragma unroll
        for (int i = 0; i < 2; ++i)
            #pragma unroll
            for (int j = 0; j < 2; ++j)
                acc[i][j] = __builtin_amdgcn_mfma_f32_16x16x32_bf16(
                    af[i], bfr[j], acc[i][j], 0, 0, 0);
    }

    float* dst = ckvT + ((size_t)bh * NCHUNK + c) * 4096;
    #pragma unroll
    for (int i = 0; i < 2; ++i) {
        int dv = wr * 32 + i * 16 + l4 * 4;
        #pragma unroll
        for (int j = 0; j < 2; ++j) {
            int dk = wc * 32 + j * 16 + l15;
            #pragma unroll
            for (int q = 0; q < 4; ++q)
                dst[(dv + q) * 64 + dk] = acc[i][j][q];
        }
    }
}

// ---------------------------------------------------------------------------
// Kernel 3: exclusive prefix over chunks, in place (layout-agnostic).
// ---------------------------------------------------------------------------
__global__ __launch_bounds__(256) void k_prefix(float* __restrict__ ckv)
{
    int id = blockIdx.x * blockDim.x + threadIdx.x;   // 0..32767
    int bh = id >> 10, i4 = id & 1023;
    float4 run = {0.f, 0.f, 0.f, 0.f};
    float* base = ckv + (size_t)bh * NCHUNK * 4096 + (size_t)i4 * 4;
    for (int c = 0; c < NCHUNK; ++c) {
        float4* p = reinterpret_cast<float4*>(base + (size_t)c * 4096);
        float4 v = *p;
        *p = run;
        run.x += v.x; run.y += v.y; run.z += v.z; run.w += v.w;
    }
}

// ---------------------------------------------------------------------------
// Kernel 4: per-chunk output (MFMA). out = 0.125*( tril(Q K^T) @ V + Q @ P )
// Q,K natural; Vt natural; P staged from ckvT (fp32->bf16, direct copy since
// ckvT[dv][dk] = P[dk][dv] is exactly the B^T layout QP needs). attn bf16.
// ---------------------------------------------------------------------------
__global__ __launch_bounds__(256) void k_chunkout(
    const unsigned short* __restrict__ qslab, const unsigned short* __restrict__ kslab,
    const unsigned short* __restrict__ vtb,  const float* __restrict__ ckvT,
    unsigned short* __restrict__ attnbf)
{
    const int c = blockIdx.x, bh = blockIdx.y;
    const int b = bh >> 4, h = bh & 15;
    const int colb = h * 64, t0 = c * CHUNK;

    __shared__ short Qs[64 * 64];
    __shared__ short Ksn[64 * 64];
    __shared__ short Vts[64 * 64];
    __shared__ short PTs[64 * 72];
    __shared__ short Ss[64 * 72];

    const int tid = threadIdx.x;
    const int lane = tid & 63, wave = tid >> 6;
    const int wr = wave >> 1, wc = wave & 1;
    const int l15 = lane & 15, l4 = lane >> 4;

    #pragma unroll
    for (int l = 0; l < 2; ++l) {
        int off = l * 4096 + tid * 16;
        int row = off >> 7, kb = off & 127;
        size_t nat = ((size_t)b * 1048576 + (size_t)(t0 + row) * E_DIM + colb) * 2 + kb;
        gload_lds16((const char*)qslab + nat, (char*)Qs + off);
        gload_lds16((const char*)kslab + nat, (char*)Ksn + off);
        size_t trn = (((size_t)(b * 1024 + colb + row)) * 1024 + t0) * 2 + kb;
        gload_lds16((const char*)vtb + trn, (char*)Vts + off);
    }
    {   // P stage: fp32 -> bf16, direct copy into padded [64][72]
        const float* P = ckvT + ((size_t)bh * NCHUNK + c) * 4096;
        #pragma unroll
        for (int l = 0; l < 4; ++l) {
            int u = tid + 256 * l;
            int dv = u >> 4, dk4 = (u & 15) * 4;
            float4 f = *reinterpret_cast<const float4*>(&P[dv * 64 + dk4]);
            ushort4 w; w.x = f2bf(f.x); w.y = f2bf(f.y); w.z = f2bf(f.z); w.w = f2bf(f.w);
            *reinterpret_cast<ushort4*>(&PTs[dv * 72 + dk4]) = w;
        }
    }
    __syncthreads();

    // Phase 1: S = Q K^T (contract over d)
    f32x4 sacc[2][2] = {};
    #pragma unroll
    for (int kk = 0; kk < 64; kk += 32) {
        bf16x8 af[2], bfr[2];
        #pragma unroll
        for (int i = 0; i < 2; ++i)
            af[i] = *reinterpret_cast<const bf16x8*>(
                        &Qs[(wr * 32 + i * 16 + l15) * 64 + kk + l4 * 8]);
        #pragma unroll
        for (int j = 0; j < 2; ++j)
            bfr[j] = *reinterpret_cast<const bf16x8*>(
                        &Ksn[(wc * 32 + j * 16 + l15) * 64 + kk + l4 * 8]);
        #pragma unroll
        for (int i = 0; i < 2; ++i)
            #pragma unroll
            for (int j = 0; j < 2; ++j)
                sacc[i][j] = __builtin_amdgcn_mfma_f32_16x16x32_bf16(
                    af[i], bfr[j], sacc[i][j], 0, 0, 0);
    }
    // mask (causal, inclusive diagonal) + cvt -> Ss
    #pragma unroll
    for (int i = 0; i < 2; ++i) {
        int qr = wr * 32 + i * 16 + l4 * 4;
        #pragma unroll
        for (int j = 0; j < 2; ++j) {
            int kr = wc * 32 + j * 16 + l15;
            #pragma unroll
            for (int q = 0; q < 4; ++q)
                Ss[(qr + q) * 72 + kr] =
                    (kr <= qr + q) ? (short)f2bf(sacc[i][j][q]) : (short)0;
        }
    }
    __syncthreads();

    // Phase 2: O = S V (contract over s) ; Phase 3: O += Q P (contract over dk)
    f32x4 oacc[2][2] = {};
    #pragma unroll
    for (int kk = 0; kk < 64; kk += 32) {
        bf16x8 af[2], bfr[2];
        #pragma unroll
        for (int i = 0; i < 2; ++i)
            af[i] = *reinterpret_cast<const bf16x8*>(
                        &Ss[(wr * 32 + i * 16 + l15) * 72 + kk + l4 * 8]);
        #pragma unroll
        for (int j = 0; j < 2; ++j)
            bfr[j] = *reinterpret_cast<const bf16x8*>(
                        &Vts[(wc * 32 + j * 16 + l15) * 64 + kk + l4 * 8]);
        #pragma unroll
        for (int i = 0; i < 2; ++i)
            #pragma unroll
            for (int j = 0; j < 2; ++j)
                oacc[i][j] = __builtin_amdgcn_mfma_f32_16x16x32_bf16(
                    af[i], bfr[j], oacc[i][j], 0, 0, 0);
    }
    #pragma unroll
    for (int kk = 0; kk < 64; kk += 32) {
        bf16x8 af[2], bfr[2];
        #pragma unroll
        for (int i = 0; i < 2; ++i)
            af[i] = *reinterpret_cast<const bf16x8*>(
                        &Qs[(wr * 32 + i * 16 + l15) * 64 + kk + l4 * 8]);
        #pragma unroll
        for (int j = 0; j < 2; ++j)
            bfr[j] = *reinterpret_cast<const bf16x8*>(
                        &PTs[(wc * 32 + j * 16 + l15) * 72 + kk + l4 * 8]);
        #pragma unroll
        for (int i = 0; i < 2; ++i)
            #pragma unroll
            for (int j = 0; j < 2; ++j)
                oacc[i][j] = __builtin_amdgcn_mfma_f32_16x16x32_bf16(
                    af[i], bfr[j], oacc[i][j], 0, 0, 0);
    }

    #pragma unroll
    for (int i = 0; i < 2; ++i) {
        int qr = wr * 32 + i * 16 + l4 * 4;
        #pragma unroll
        for (int j = 0; j < 2; ++j) {
            int dv = wc * 32 + j * 16 + l15;
            #pragma unroll
            for (int q = 0; q < 4; ++q)
                attnbf[(size_t)b * 1048576 + (size_t)(t0 + qr + q) * E_DIM + colb + dv] =
                    f2bf(oacc[i][j][q] * 0.125f);
        }
    }
}

// ---------------------------------------------------------------------------
// Kernel 5: out-projection GEMM, 64x128 tile. A = attnbf (b-major, gathered
// per r = t*2+b), W = Wobf. fp32 output rows (t,b).
// ---------------------------------------------------------------------------
__global__ __launch_bounds__(256) void k_gout(
    const unsigned short* __restrict__ attnbf, const unsigned short* __restrict__ Wobf,
    const float* __restrict__ bias, float* __restrict__ out)
{
    const int nBase = blockIdx.x * 128;
    const int mBase = blockIdx.y * 64;        // r-space (t*2+b)

    __shared__ short As[64 * 64];
    __shared__ short Bs[128 * 64];

    const int tid = threadIdx.x;
    const int lane = tid & 63, wave = tid >> 6;
    const int wr = wave >> 1, wc = wave & 1;
    const int l15 = lane & 15, l4 = lane >> 4;

    f32x4 acc[2][4] = {};

    for (int k0 = 0; k0 < E_DIM; k0 += 64) {
        #pragma unroll
        for (int l = 0; l < 4; ++l) {
            int off = l * 4096 + tid * 16;
            int row = off >> 7, kb = off & 127;
            gload_lds16((const char*)Wobf + ((size_t)(nBase + row) * E_DIM + k0) * 2 + kb,
                        (char*)Bs + off);
        }
        #pragma unroll
        for (int l = 0; l < 2; ++l) {
            int off = l * 4096 + tid * 16;
            int row = off >> 7, kb = off & 127;
            int r = mBase + row, t = r >> 1, bb = r & 1;
            gload_lds16((const char*)attnbf +
                            ((size_t)bb * 1048576 + (size_t)t * E_DIM + k0) * 2 + kb,
                        (char*)As + off);
        }
        __syncthreads();

        #pragma unroll
        for (int kk = 0; kk < 64; kk += 32) {
            bf16x8 af[2], bfr[4];
            #pragma unroll
            for (int i = 0; i < 2; ++i)
                af[i] = *reinterpret_cast<const bf16x8*>(
                            &As[(wr * 32 + i * 16 + l15) * 64 + kk + l4 * 8]);
            #pragma unroll
            for (int j = 0; j < 4; ++j)
                bfr[j] = *reinterpret_cast<const bf16x8*>(
                            &Bs[(wc * 64 + j * 16 + l15) * 64 + kk + l4 * 8]);
            #pragma unroll
            for (int i = 0; i < 2; ++i)
                #pragma unroll
                for (int j = 0; j < 4; ++j)
                    acc[i][j] = __builtin_amdgcn_mfma_f32_16x16x32_bf16(
                        af[i], bfr[j], acc[i][j], 0, 0, 0);
        }
        __syncthreads();
    }

    #pragma unroll
    for (int i = 0; i < 2; ++i) {
        int r0 = mBase + wr * 32 + i * 16 + l4 * 4;
        #pragma unroll
        for (int j = 0; j < 4; ++j) {
            int col = nBase + wc * 64 + j * 16 + l15;
            float bv = bias[col];
            #pragma unroll
            for (int q = 0; q < 4; ++q)
                out[(size_t)(r0 + q) * E_DIM + col] = acc[i][j][q] + bv;
        }
    }
}

// ---------------------------------------------------------------------------
extern "C" void kernel_launch(void* const* d_in, const int* in_sizes, int n_in,
                              void* d_out, int out_size, void* d_ws, size_t ws_size,
                              hipStream_t stream)
{
    const float* q_in  = (const float*)d_in[0];
    const float* k_in  = (const float*)d_in[1];
    const float* v_in  = (const float*)d_in[2];
    const float* w_in  = (const float*)d_in[3];
    const float* b_in  = (const float*)d_in[4];
    const float* w_out = (const float*)d_in[5];
    const float* b_out = (const float*)d_in[6];

    // ws layout (36 MiB):
    //   [ 0, 6M)  Wibf bf16        [ 6M, 8M)  Wobf bf16
    //   [ 8M,12M) qslab bf16 [b][t][e]   [12M,16M) kslab bf16 [b][t][e]
    //   [16M,20M) ktb bf16 [b][e][t]     [20M,24M) vtb bf16 [b][e][t]
    //   [24M,32M) ckvT fp32 [bh][c][dv][dk]
    //   [32M,36M) attnbf bf16 [b][t][e]
    char* w = (char*)d_ws;
    unsigned short* Wibf   = (unsigned short*)w;
    unsigned short* Wobf   = (unsigned short*)(w + 6291456);
    unsigned short* qslab  = (unsigned short*)(w + 8388608);
    unsigned short* kslab  = (unsigned short*)(w + 12582912);
    unsigned short* ktb    = (unsigned short*)(w + 16777216);
    unsigned short* vtb    = (unsigned short*)(w + 20971520);
    float*          ckvT   = (float*)(w + 25165824);
    unsigned short* attnbf = (unsigned short*)(w + 33554432);
    float* outp = (float*)d_out;

    k_castw<<<2048, 256, 0, stream>>>(w_in, w_out, Wibf);

    k_gin<<<dim3(8, 32, 3), 256, 0, stream>>>(
        q_in, k_in, v_in, Wibf, b_in, qslab, kslab, ktb, vtb);

    k_chunkkv<<<dim3(NCHUNK, BH), 256, 0, stream>>>(ktb, vtb, ckvT);
    k_prefix<<<dim3(BH * 1024 / 256), 256, 0, stream>>>(ckvT);
    k_chunkout<<<dim3(NCHUNK, BH), 256, 0, stream>>>(qslab, kslab, vtb, ckvT, attnbf);

    k_gout<<<dim3(8, 32), 256, 0, stream>>>(attnbf, Wobf, b_out, outp);
}